// Round 12
// baseline (141.174 us; speedup 1.0000x reference)
//
#include <hip/hip_runtime.h>
#include <hip/hip_bf16.h>

#define HIDDEN 256
#define HEADS 8
#define HEAD_DIM 32
#define NUM_RBF 32
#define K_PTS 4096
#define N_ATOMS 2048
#define B_MOL 32
#define ATOMS_PER_MOL (N_ATOMS / B_MOL)   // 64

typedef __attribute__((ext_vector_type(8))) short bf16x8;
typedef __attribute__((ext_vector_type(4))) float f32x4;

// -------------------------------------------------------------------------
// K0: prepW — weight transposes (4 mats x 64 tiles of 32x32). WT[c][d]=bf16(W[d][c])
// -------------------------------------------------------------------------
__global__ __launch_bounds__(256) void prepW_kernel(
    const float* __restrict__ Wq, const float* __restrict__ Wk,
    const float* __restrict__ Wv, const float* __restrict__ Wo,
    __hip_bfloat16* __restrict__ WqT, __hip_bfloat16* __restrict__ WkT,
    __hip_bfloat16* __restrict__ WvT, __hip_bfloat16* __restrict__ WoT) {
    __shared__ float tile[32][33];
    const int t = blockIdx.x, tid = threadIdx.x;
    const int matId = t >> 6, tileId = t & 63;
    const int tr = (tileId >> 3) * 32, tc = (tileId & 7) * 32;
    const float* __restrict__ Ws = (matId == 0) ? Wq : (matId == 1) ? Wk : (matId == 2) ? Wv : Wo;
    __hip_bfloat16* __restrict__ Wd = (matId == 0) ? WqT : (matId == 1) ? WkT : (matId == 2) ? WvT : WoT;

    const int r = tid >> 3, cq = (tid & 7) * 4;
    const float4 in = *(const float4*)&Ws[(size_t)(tr + r) * HIDDEN + tc + cq];
    tile[r][cq + 0] = in.x; tile[r][cq + 1] = in.y;
    tile[r][cq + 2] = in.z; tile[r][cq + 3] = in.w;
    __syncthreads();
    __hip_bfloat16 o[4];
    o[0] = __float2bfloat16(tile[cq + 0][r]);
    o[1] = __float2bfloat16(tile[cq + 1][r]);
    o[2] = __float2bfloat16(tile[cq + 2][r]);
    o[3] = __float2bfloat16(tile[cq + 3][r]);
    *(uint2*)(Wd + (size_t)(tc + r) * HIDDEN + tr + cq) = *(const uint2*)o;
}

// -------------------------------------------------------------------------
// K1: fused QKV MFMA GEMM, col-split: each block = 16 rows x 128 cols.
// blocks [0,512): Q (256 row-blocks x 2 col-halves);
// blocks [512,768): K+V (128 row-blocks x 2 col-halves).
// Q -> bf16 row-major; K -> bf16 row-major; V -> mol-tiled vtm[mol][col][atom].
// -------------------------------------------------------------------------
__device__ __forceinline__ bf16x8 cvt8(const float* p) {
    const float4 lo = *(const float4*)p;
    const float4 hi = *(const float4*)(p + 4);
    __hip_bfloat16 t[8];
    t[0] = __float2bfloat16(lo.x); t[1] = __float2bfloat16(lo.y);
    t[2] = __float2bfloat16(lo.z); t[3] = __float2bfloat16(lo.w);
    t[4] = __float2bfloat16(hi.x); t[5] = __float2bfloat16(hi.y);
    t[6] = __float2bfloat16(hi.z); t[7] = __float2bfloat16(hi.w);
    return *(const bf16x8*)t;
}

__global__ __launch_bounds__(256) void qkv4_kernel(
    const float* __restrict__ hp, const float* __restrict__ ha,
    const __hip_bfloat16* __restrict__ WqT, const float* __restrict__ bq, __hip_bfloat16* __restrict__ qb,
    const __hip_bfloat16* __restrict__ WkT, const float* __restrict__ bk, __hip_bfloat16* __restrict__ kb,
    const __hip_bfloat16* __restrict__ WvT, const float* __restrict__ bv, __hip_bfloat16* __restrict__ vtm) {
    const int b = blockIdx.x;
    const bool isQ = (b < 512);
    const int rb = isQ ? (b >> 1) : ((b - 512) >> 1);
    const int ch = isQ ? (b & 1) : ((b - 512) & 1);
    const float* __restrict__ A = isQ ? hp : ha;
    const __hip_bfloat16* __restrict__ W0T = isQ ? WqT : WkT;
    const float* __restrict__ b0 = isQ ? bq : bk;
    const int r0 = rb * 16;

    const int wave = threadIdx.x >> 6, lane = threadIdx.x & 63;
    const int c0 = ch * 128 + wave * 32;          // this wave's 32-col slice
    const int lrow = lane & 15, kgrp = lane >> 4;

    bf16x8 af[8];
    const float* Arow = A + (size_t)(r0 + lrow) * HIDDEN + kgrp * 8;
#pragma unroll
    for (int ks = 0; ks < 8; ++ks)
        af[ks] = cvt8(Arow + ks * 32);

    f32x4 acc0[2], acc1[2];
#pragma unroll
    for (int cc = 0; cc < 2; ++cc) {
        acc0[cc] = (f32x4){0.f, 0.f, 0.f, 0.f};
        acc1[cc] = (f32x4){0.f, 0.f, 0.f, 0.f};
    }

#pragma unroll
    for (int cc = 0; cc < 2; ++cc) {
        const short* W0r = (const short*)W0T + (size_t)(c0 + cc * 16 + lrow) * HIDDEN + kgrp * 8;
#pragma unroll
        for (int ks = 0; ks < 8; ++ks)
            acc0[cc] = __builtin_amdgcn_mfma_f32_16x16x32_bf16(
                af[ks], *(const bf16x8*)(W0r + ks * 32), acc0[cc], 0, 0, 0);
        if (!isQ) {
            const short* W1r = (const short*)WvT + (size_t)(c0 + cc * 16 + lrow) * HIDDEN + kgrp * 8;
#pragma unroll
            for (int ks = 0; ks < 8; ++ks)
                acc1[cc] = __builtin_amdgcn_mfma_f32_16x16x32_bf16(
                    af[ks], *(const bf16x8*)(W1r + ks * 32), acc1[cc], 0, 0, 0);
        }
    }

    const int colb = lane & 15;
    const int rowb = (lane >> 4) * 4;
#pragma unroll
    for (int cc = 0; cc < 2; ++cc) {
        const int cgl = c0 + cc * 16 + colb;
        const float bias0 = b0[cgl];
        if (isQ) {
#pragma unroll
            for (int rg = 0; rg < 4; ++rg)
                qb[(size_t)(r0 + rowb + rg) * HIDDEN + cgl] = __float2bfloat16(acc0[cc][rg] + bias0);
        } else {
            const float bias1 = bv[cgl];
            const int mol = r0 >> 6;
            const int abase = (r0 & 63) + rowb;
            __hip_bfloat16 vo[4];
#pragma unroll
            for (int rg = 0; rg < 4; ++rg) {
                kb[(size_t)(r0 + rowb + rg) * HIDDEN + cgl] = __float2bfloat16(acc0[cc][rg] + bias0);
                vo[rg] = __float2bfloat16(acc1[cc][rg] + bias1);
            }
            *(uint2*)(vtm + (size_t)mol * (HIDDEN * ATOMS_PER_MOL) +
                      (size_t)cgl * ATOMS_PER_MOL + abase) = *(const uint2*)vo;
        }
    }
}

// -------------------------------------------------------------------------
// K2: attn_mfma4 — block = 4 points, 8 waves (512 thr), grid 1024 (4 blk/CU).
// Phase 1 (wave = (pt, atom-half), 32 lanes): RBF bias -> bias_lds[h][atom][pt]
// Phase 2+3 (wave = 1 head): QK^T MFMA + softmax + PV MFMA
// Phase 4: out-proj MFMA (wave = 32 cols, 4 valid rows) + residual + LN
// -------------------------------------------------------------------------
#define AGG_PAD (HIDDEN + 16)

__global__ __launch_bounds__(512, 8) void attn_mfma4_kernel(
    const __hip_bfloat16* __restrict__ qb, const __hip_bfloat16* __restrict__ kb,
    const __hip_bfloat16* __restrict__ vtm,
    const float* __restrict__ pos_point, const float* __restrict__ pos_atom,
    const float* __restrict__ W_rbf, const float* __restrict__ b_rbf,
    const float* __restrict__ centers,
    const int* __restrict__ point_batch, const int* __restrict__ atom_batch,
    const __hip_bfloat16* __restrict__ WoT, const float* __restrict__ bo,
    const float* __restrict__ h_point,
    const float* __restrict__ gamma, const float* __restrict__ beta,
    float* __restrict__ out) {
    __shared__ float wrbf_lds[NUM_RBF][HEADS];       // 1 KB
    __shared__ float cent_lds[NUM_RBF];
    __shared__ float brbf_lds[HEADS];
    __shared__ float bias_lds[HEADS][ATOMS_PER_MOL + 4][4];  // 8.7 KB (+4 pad rows for b128 overreach)
    __shared__ __hip_bfloat16 p_lds[HEADS][4][72];   // 4.6 KB [h][pt][atom]
    __shared__ __hip_bfloat16 agg_lds[4][AGG_PAD];   // 2.2 KB
    __shared__ float x_lds[4][260];                  // 4.2 KB
    __shared__ float red_s[4][4];
    __shared__ float red_q[4][4];

    const int tid = threadIdx.x, wave = tid >> 6, lane = tid & 63;
    const int j0 = blockIdx.x * 4;
    const float scale = 0.17677669529663687f;  // 32^-0.5

    if (tid < NUM_RBF * HEADS) ((float*)wrbf_lds)[tid] = W_rbf[tid];
    if (tid < NUM_RBF) cent_lds[tid] = centers[tid];
    if (tid < HEADS) brbf_lds[tid] = b_rbf[tid];
    if (tid < 128) {   // zero the 4 pad rows: h = tid>>4, row 64 + (tid>>2)&3, p = tid&3
        bias_lds[tid >> 4][ATOMS_PER_MOL + ((tid >> 2) & 3)][tid & 3] = 0.0f;
    }
    __syncthreads();

    const int m = point_batch[j0];
    const int mbase = m * ATOMS_PER_MOL;

    // ---------------- Phase 1: RBF bias (wave = (pt, half), 32 lanes) ----
    if (lane < 32) {
        const int ptl = wave >> 1;               // 0..3
        const int atom = (wave & 1) * 32 + lane; // 0..63
        const int n = mbase + atom;
        const bool valid = (atom_batch[n] == m);
        const int j = j0 + ptl;

        const float dx = pos_point[j * 3 + 0] - pos_atom[n * 3 + 0];
        const float dy = pos_point[j * 3 + 1] - pos_atom[n * 3 + 1];
        const float dz = pos_point[j * 3 + 2] - pos_atom[n * 3 + 2];
        const float dist = sqrtf(fmaxf(dx * dx + dy * dy + dz * dz, 0.0f));

        float bias[HEADS];
#pragma unroll
        for (int h = 0; h < HEADS; ++h) bias[h] = brbf_lds[h];
#pragma unroll
        for (int r = 0; r < NUM_RBF; ++r) {
            const float dd = dist - cent_lds[r];
            const float e = __expf(-16.0f * dd * dd);   // width = (8/32)^2 -> -1/w = -16
#pragma unroll
            for (int h = 0; h < HEADS; ++h)
                bias[h] += e * wrbf_lds[r][h];
        }
#pragma unroll
        for (int h = 0; h < HEADS; ++h)
            bias_lds[h][atom][ptl] = valid ? bias[h] : -1e30f;
    }
    __syncthreads();

    // ---------------- Phase 2+3: wave = 1 head ---------------------------
    const int c = lane & 15, kgrp = lane >> 4;
    const int h = wave;
    {
        // A fragment: Q rows = 4 points (rows 4-15 duplicate, outputs unused)
        const bf16x8 aq = *(const bf16x8*)((const short*)qb +
                          (size_t)(j0 + (c & 3)) * HIDDEN + h * HEAD_DIM + kgrp * 8);

        // QK^T: one MFMA per 16-atom tile (K=32 = head_dim)
        f32x4 sacc[4];
#pragma unroll
        for (int t = 0; t < 4; ++t) {
            const bf16x8 bk_ = *(const bf16x8*)((const short*)kb +
                               (size_t)(mbase + c + 16 * t) * HIDDEN + h * HEAD_DIM + kgrp * 8);
            sacc[t] = __builtin_amdgcn_mfma_f32_16x16x32_bf16(
                aq, bk_, (f32x4){0.f, 0.f, 0.f, 0.f}, 0, 0, 0);
        }

        // scores + bias (b128 per tile; kgrp>0 overreads land in pad rows)
        float s[4][4];   // [tile][reg = pt row]
#pragma unroll
        for (int t = 0; t < 4; ++t) {
            const f32x4 bv = *(const f32x4*)&bias_lds[h][c + 16 * t][kgrp * 4];
#pragma unroll
            for (int r = 0; r < 4; ++r)
                s[t][r] = sacc[t][r] * scale + bv[r];
        }
#pragma unroll
        for (int r = 0; r < 4; ++r) {
            float mx = fmaxf(fmaxf(s[0][r], s[1][r]), fmaxf(s[2][r], s[3][r]));
#pragma unroll
            for (int off = 1; off <= 8; off <<= 1)
                mx = fmaxf(mx, __shfl_xor(mx, off));
            float e0 = __expf(s[0][r] - mx);
            float e1 = __expf(s[1][r] - mx);
            float e2 = __expf(s[2][r] - mx);
            float e3 = __expf(s[3][r] - mx);
            float ss = e0 + e1 + e2 + e3;
#pragma unroll
            for (int off = 1; off <= 8; off <<= 1)
                ss += __shfl_xor(ss, off);
            const float inv = 1.0f / ss;
            if (kgrp == 0) {   // rows 0-3 = valid points
                p_lds[h][r][c + 16 * 0] = __float2bfloat16(e0 * inv);
                p_lds[h][r][c + 16 * 1] = __float2bfloat16(e1 * inv);
                p_lds[h][r][c + 16 * 2] = __float2bfloat16(e2 * inv);
                p_lds[h][r][c + 16 * 3] = __float2bfloat16(e3 * inv);
            }
        }

        // PV: A = P (LDS, row=pt), B = V (mol-tiled [col][atom]), 2 x 2 MFMAs
        const short* vbase = (const short*)vtm + (size_t)m * (HIDDEN * ATOMS_PER_MOL);
#pragma unroll
        for (int t2 = 0; t2 < 2; ++t2) {
            f32x4 pacc = (f32x4){0.f, 0.f, 0.f, 0.f};
#pragma unroll
            for (int ks = 0; ks < 2; ++ks) {
                const bf16x8 ap = *(const bf16x8*)&p_lds[h][c & 3][ks * 32 + kgrp * 8];
                const bf16x8 bvv = *(const bf16x8*)(vbase +
                                   (size_t)(h * HEAD_DIM + t2 * 16 + c) * ATOMS_PER_MOL +
                                   ks * 32 + kgrp * 8);
                pacc = __builtin_amdgcn_mfma_f32_16x16x32_bf16(ap, bvv, pacc, 0, 0, 0);
            }
            if (kgrp == 0) {
#pragma unroll
                for (int r = 0; r < 4; ++r)
                    agg_lds[r][h * HEAD_DIM + t2 * 16 + c] = __float2bfloat16(pacc[r]);
            }
        }
    }
    __syncthreads();

    // ---------------- Phase 4: out-projection MFMA (wave = 32 cols) ------
    const int c0 = wave * 32;
    const int lrow = lane & 15, kgrp2 = lane >> 4;
    bf16x8 af[8];
    const bf16x8 zf = {0, 0, 0, 0, 0, 0, 0, 0};
#pragma unroll
    for (int ks = 0; ks < 8; ++ks)
        af[ks] = (lrow < 4) ? *(const bf16x8*)(&agg_lds[lrow & 3][kgrp2 * 8 + ks * 32]) : zf;

    f32x4 oacc[2];
#pragma unroll
    for (int cc = 0; cc < 2; ++cc) oacc[cc] = (f32x4){0.f, 0.f, 0.f, 0.f};
#pragma unroll
    for (int cc = 0; cc < 2; ++cc) {
        const short* Wr = (const short*)WoT + (size_t)(c0 + cc * 16 + lrow) * HIDDEN + kgrp2 * 8;
#pragma unroll
        for (int ks = 0; ks < 8; ++ks)
            oacc[cc] = __builtin_amdgcn_mfma_f32_16x16x32_bf16(
                af[ks], *(const bf16x8*)(Wr + ks * 32), oacc[cc], 0, 0, 0);
    }

    const int colb = lane & 15;
    const int rowb = (lane >> 4) * 4;
#pragma unroll
    for (int cc = 0; cc < 2; ++cc) {
        const int cgl = c0 + cc * 16 + colb;
        const float bias_o = bo[cgl];
#pragma unroll
        for (int rg = 0; rg < 4; ++rg) {
            const int rl = rowb + rg;
            if (rl < 4)
                x_lds[rl][cgl] = oacc[cc][rg] + bias_o + h_point[(size_t)(j0 + rl) * HIDDEN + cgl];
        }
    }
    __syncthreads();

    // ---------------- LN: 512 threads, col = tid&255, 2 rows each --------
    const int col = tid & 255;
    const int half = tid >> 8;             // 0: rows 0-1, 1: rows 2-3
    const int ln = col & 63, wv = col >> 6;
    float xv[2];
#pragma unroll
    for (int r = 0; r < 2; ++r) {
        const int rr = half * 2 + r;
        xv[r] = x_lds[rr][col];
        float s = xv[r], qq = xv[r] * xv[r];
#pragma unroll
        for (int off = 32; off > 0; off >>= 1) {
            s += __shfl_xor(s, off);
            qq += __shfl_xor(qq, off);
        }
        if (ln == 0) { red_s[rr][wv] = s; red_q[rr][wv] = qq; }
    }
    __syncthreads();

    const float gc = gamma[col], bc = beta[col];
#pragma unroll
    for (int r = 0; r < 2; ++r) {
        const int rr = half * 2 + r;
        const float mean = (red_s[rr][0] + red_s[rr][1] + red_s[rr][2] + red_s[rr][3]) * (1.0f / HIDDEN);
        const float ex2  = (red_q[rr][0] + red_q[rr][1] + red_q[rr][2] + red_q[rr][3]) * (1.0f / HIDDEN);
        const float var = ex2 - mean * mean;
        out[(size_t)(j0 + rr) * HIDDEN + col] = (xv[r] - mean) * rsqrtf(var + 1e-5f) * gc + bc;
    }
}

// -------------------------------------------------------------------------
extern "C" void kernel_launch(void* const* d_in, const int* in_sizes, int n_in,
                              void* d_out, int out_size, void* d_ws, size_t ws_size,
                              hipStream_t stream) {
    const float* h_point   = (const float*)d_in[0];
    const float* h_atom    = (const float*)d_in[1];
    const float* pos_point = (const float*)d_in[2];
    const float* pos_atom  = (const float*)d_in[3];
    const float* Wq        = (const float*)d_in[4];
    const float* bq        = (const float*)d_in[5];
    const float* Wk        = (const float*)d_in[6];
    const float* bk        = (const float*)d_in[7];
    const float* Wv        = (const float*)d_in[8];
    const float* bv        = (const float*)d_in[9];
    const float* Wo        = (const float*)d_in[10];
    const float* bo        = (const float*)d_in[11];
    const float* W_rbf     = (const float*)d_in[12];
    const float* b_rbf     = (const float*)d_in[13];
    const float* centers   = (const float*)d_in[14];
    const float* gamma     = (const float*)d_in[15];
    const float* beta      = (const float*)d_in[16];
    const int*   point_batch = (const int*)d_in[17];
    const int*   atom_batch  = (const int*)d_in[18];
    float* out = (float*)d_out;

    __hip_bfloat16* qb = (__hip_bfloat16*)d_ws;                 // 4096*256 bf16
    __hip_bfloat16* kb = qb + (size_t)K_PTS * HIDDEN;           // 2048*256 bf16
    __hip_bfloat16* vtm = kb + (size_t)N_ATOMS * HIDDEN;        // 32 x 256 x 64 bf16 (mol-tiled V^T)
    __hip_bfloat16* WqT = vtm + (size_t)HIDDEN * N_ATOMS;
    __hip_bfloat16* WkT = WqT + HIDDEN * HIDDEN;
    __hip_bfloat16* WvT = WkT + HIDDEN * HIDDEN;
    __hip_bfloat16* WoT = WvT + HIDDEN * HIDDEN;

    prepW_kernel<<<256, 256, 0, stream>>>(Wq, Wk, Wv, Wo, WqT, WkT, WvT, WoT);

    qkv4_kernel<<<768, 256, 0, stream>>>(h_point, h_atom,
                                         WqT, bq, qb,
                                         WkT, bk, kb,
                                         WvT, bv, vtm);

    attn_mfma4_kernel<<<K_PTS / 4, 512, 0, stream>>>(qb, kb, vtm,
                                                     pos_point, pos_atom,
                                                     W_rbf, b_rbf, centers,
                                                     point_batch, atom_batch,
                                                     WoT, bo, h_point, gamma, beta,
                                                     out);
}

// Round 13
// 138.051 us; speedup vs baseline: 1.0226x; 1.0226x over previous
//
#include <hip/hip_runtime.h>
#include <hip/hip_bf16.h>

#define HIDDEN 256
#define HEADS 8
#define HEAD_DIM 32
#define NUM_RBF 32
#define K_PTS 4096
#define N_ATOMS 2048
#define B_MOL 32
#define ATOMS_PER_MOL (N_ATOMS / B_MOL)   // 64

typedef __attribute__((ext_vector_type(8))) short bf16x8;
typedef __attribute__((ext_vector_type(4))) float f32x4;

// -------------------------------------------------------------------------
// K0: prepW — weight transposes (4 mats x 64 tiles of 32x32). WT[c][d]=bf16(W[d][c])
// -------------------------------------------------------------------------
__global__ __launch_bounds__(256) void prepW_kernel(
    const float* __restrict__ Wq, const float* __restrict__ Wk,
    const float* __restrict__ Wv, const float* __restrict__ Wo,
    __hip_bfloat16* __restrict__ WqT, __hip_bfloat16* __restrict__ WkT,
    __hip_bfloat16* __restrict__ WvT, __hip_bfloat16* __restrict__ WoT) {
    __shared__ float tile[32][33];
    const int t = blockIdx.x, tid = threadIdx.x;
    const int matId = t >> 6, tileId = t & 63;
    const int tr = (tileId >> 3) * 32, tc = (tileId & 7) * 32;
    const float* __restrict__ Ws = (matId == 0) ? Wq : (matId == 1) ? Wk : (matId == 2) ? Wv : Wo;
    __hip_bfloat16* __restrict__ Wd = (matId == 0) ? WqT : (matId == 1) ? WkT : (matId == 2) ? WvT : WoT;

    const int r = tid >> 3, cq = (tid & 7) * 4;
    const float4 in = *(const float4*)&Ws[(size_t)(tr + r) * HIDDEN + tc + cq];
    tile[r][cq + 0] = in.x; tile[r][cq + 1] = in.y;
    tile[r][cq + 2] = in.z; tile[r][cq + 3] = in.w;
    __syncthreads();
    __hip_bfloat16 o[4];
    o[0] = __float2bfloat16(tile[cq + 0][r]);
    o[1] = __float2bfloat16(tile[cq + 1][r]);
    o[2] = __float2bfloat16(tile[cq + 2][r]);
    o[3] = __float2bfloat16(tile[cq + 3][r]);
    *(uint2*)(Wd + (size_t)(tc + r) * HIDDEN + tr + cq) = *(const uint2*)o;
}

// -------------------------------------------------------------------------
// K1: fused QKV GEMM + RBF-bias table, one dispatch (bias blocks fill the
// idle CUs under the MFMA GEMM).
// blocks [0,256): Q; [256,384): K+V; [384,896): bias table.
// bias_g layout = attn's bias_lds exactly: [blk8][h][atom 64][pt 8] f32.
// -------------------------------------------------------------------------
__device__ __forceinline__ bf16x8 cvt8(const float* p) {
    const float4 lo = *(const float4*)p;
    const float4 hi = *(const float4*)(p + 4);
    __hip_bfloat16 t[8];
    t[0] = __float2bfloat16(lo.x); t[1] = __float2bfloat16(lo.y);
    t[2] = __float2bfloat16(lo.z); t[3] = __float2bfloat16(lo.w);
    t[4] = __float2bfloat16(hi.x); t[5] = __float2bfloat16(hi.y);
    t[6] = __float2bfloat16(hi.z); t[7] = __float2bfloat16(hi.w);
    return *(const bf16x8*)t;
}

__global__ __launch_bounds__(256) void qkv_bias_kernel(
    const float* __restrict__ hp, const float* __restrict__ ha,
    const __hip_bfloat16* __restrict__ WqT, const float* __restrict__ bq, __hip_bfloat16* __restrict__ qb,
    const __hip_bfloat16* __restrict__ WkT, const float* __restrict__ bk, __hip_bfloat16* __restrict__ kb,
    const __hip_bfloat16* __restrict__ WvT, const float* __restrict__ bv, __hip_bfloat16* __restrict__ vtm,
    const float* __restrict__ pos_point, const float* __restrict__ pos_atom,
    const float* __restrict__ W_rbf, const float* __restrict__ b_rbf,
    const float* __restrict__ centers,
    const int* __restrict__ point_batch, const int* __restrict__ atom_batch,
    float* __restrict__ bias_g) {
    const int b = blockIdx.x, tid = threadIdx.x;

    if (b >= 384) {
        // ---------------- bias-table blocks (8 points x 64 atoms each) ----
        __shared__ float wrbf_s[NUM_RBF][HEADS];
        __shared__ float cent_s[NUM_RBF];
        __shared__ float brbf_s[HEADS];
        if (tid < NUM_RBF * HEADS) ((float*)wrbf_s)[tid] = W_rbf[tid];
        if (tid < NUM_RBF) cent_s[tid] = centers[tid];
        if (tid < HEADS) brbf_s[tid] = b_rbf[tid];
        __syncthreads();

        const int bb = b - 384;            // 0..511
        const int j0 = bb * 8;
        const int m = point_batch[j0];
        const int mbase = m * ATOMS_PER_MOL;
        float* bg = bias_g + (size_t)bb * (HEADS * ATOMS_PER_MOL * 8);

#pragma unroll
        for (int it = 0; it < 2; ++it) {
            const int pair = tid + it * 256;   // 0..511
            const int atom = pair >> 3;        // 0..63
            const int pt = pair & 7;           // 0..7
            const int n = mbase + atom;
            const bool valid = (atom_batch[n] == m);
            const int j = j0 + pt;

            const float dx = pos_point[j * 3 + 0] - pos_atom[n * 3 + 0];
            const float dy = pos_point[j * 3 + 1] - pos_atom[n * 3 + 1];
            const float dz = pos_point[j * 3 + 2] - pos_atom[n * 3 + 2];
            const float dist = sqrtf(fmaxf(dx * dx + dy * dy + dz * dz, 0.0f));

            float bias[HEADS];
#pragma unroll
            for (int h = 0; h < HEADS; ++h) bias[h] = brbf_s[h];
#pragma unroll
            for (int r = 0; r < NUM_RBF; ++r) {
                const float dd = dist - cent_s[r];
                const float e = __expf(-16.0f * dd * dd);   // width=(8/32)^2 -> -1/w = -16
#pragma unroll
                for (int h = 0; h < HEADS; ++h)
                    bias[h] += e * wrbf_s[r][h];
            }
#pragma unroll
            for (int h = 0; h < HEADS; ++h)
                bg[h * (ATOMS_PER_MOL * 8) + atom * 8 + pt] = valid ? bias[h] : -1e30f;
        }
        return;
    }

    // ---------------- GEMM blocks (R10 structure) ------------------------
    const bool isQ = (b < 256);
    const float* __restrict__ A = isQ ? hp : ha;
    const __hip_bfloat16* __restrict__ W0T = isQ ? WqT : WkT;
    const float* __restrict__ b0 = isQ ? bq : bk;
    const int r0 = (isQ ? b : b - 256) * 16;

    const int wave = tid >> 6, lane = tid & 63;
    const int c0 = wave * 64;
    const int lrow = lane & 15, kgrp = lane >> 4;

    bf16x8 af[8];
    const float* Arow = A + (size_t)(r0 + lrow) * HIDDEN + kgrp * 8;
#pragma unroll
    for (int ks = 0; ks < 8; ++ks)
        af[ks] = cvt8(Arow + ks * 32);

    f32x4 acc0[4], acc1[4];
#pragma unroll
    for (int cc = 0; cc < 4; ++cc) {
        acc0[cc] = (f32x4){0.f, 0.f, 0.f, 0.f};
        acc1[cc] = (f32x4){0.f, 0.f, 0.f, 0.f};
    }

#pragma unroll
    for (int cc = 0; cc < 4; ++cc) {
        const short* W0r = (const short*)W0T + (size_t)(c0 + cc * 16 + lrow) * HIDDEN + kgrp * 8;
#pragma unroll
        for (int ks = 0; ks < 8; ++ks)
            acc0[cc] = __builtin_amdgcn_mfma_f32_16x16x32_bf16(
                af[ks], *(const bf16x8*)(W0r + ks * 32), acc0[cc], 0, 0, 0);
        if (!isQ) {
            const short* W1r = (const short*)WvT + (size_t)(c0 + cc * 16 + lrow) * HIDDEN + kgrp * 8;
#pragma unroll
            for (int ks = 0; ks < 8; ++ks)
                acc1[cc] = __builtin_amdgcn_mfma_f32_16x16x32_bf16(
                    af[ks], *(const bf16x8*)(W1r + ks * 32), acc1[cc], 0, 0, 0);
        }
    }

    const int colb = lane & 15;
    const int rowb = (lane >> 4) * 4;
#pragma unroll
    for (int cc = 0; cc < 4; ++cc) {
        const int cgl = c0 + cc * 16 + colb;
        const float bias0 = b0[cgl];
        if (isQ) {
#pragma unroll
            for (int rg = 0; rg < 4; ++rg)
                qb[(size_t)(r0 + rowb + rg) * HIDDEN + cgl] = __float2bfloat16(acc0[cc][rg] + bias0);
        } else {
            const float bias1 = bv[cgl];
            const int mol = r0 >> 6;
            const int abase = (r0 & 63) + rowb;
            __hip_bfloat16 vo[4];
#pragma unroll
            for (int rg = 0; rg < 4; ++rg) {
                kb[(size_t)(r0 + rowb + rg) * HIDDEN + cgl] = __float2bfloat16(acc0[cc][rg] + bias0);
                vo[rg] = __float2bfloat16(acc1[cc][rg] + bias1);
            }
            *(uint2*)(vtm + (size_t)mol * (HIDDEN * ATOMS_PER_MOL) +
                      (size_t)cgl * ATOMS_PER_MOL + abase) = *(const uint2*)vo;
        }
    }
}

// -------------------------------------------------------------------------
// K2: attn_mfma8 — block = 8 points, 8 waves. Bias phase = 16KB copy.
// Phase 2+3 (wave = 1 head): QK^T MFMA + softmax + PV MFMA
// Phase 4: out-proj MFMA (wave = 32 cols) + residual + LN
// -------------------------------------------------------------------------
#define AGG_PAD (HIDDEN + 16)

__global__ __launch_bounds__(512, 8) void attn_mfma8_kernel(
    const __hip_bfloat16* __restrict__ qb, const __hip_bfloat16* __restrict__ kb,
    const __hip_bfloat16* __restrict__ vtm,
    const float* __restrict__ bias_g,
    const int* __restrict__ point_batch,
    const __hip_bfloat16* __restrict__ WoT, const float* __restrict__ bo,
    const float* __restrict__ h_point,
    const float* __restrict__ gamma, const float* __restrict__ beta,
    float* __restrict__ out) {
    __shared__ float bias_lds[HEADS][ATOMS_PER_MOL + 1][8];  // 16.6 KB (+1 row pad)
    __shared__ __hip_bfloat16 p_lds[HEADS][8][72];  // 9 KB [h][pt][atom]
    __shared__ __hip_bfloat16 agg_lds[8][AGG_PAD];  // 4.3 KB
    __shared__ float x_lds[8][260];                 // 8.3 KB
    __shared__ float red_s[8][4];
    __shared__ float red_q[8][4];

    const int tid = threadIdx.x, wave = tid >> 6, lane = tid & 63;
    const int j0 = blockIdx.x * 8;
    const float scale = 0.17677669529663687f;  // 32^-0.5

    // ---------------- bias copy: global (16KB, coalesced) -> LDS ---------
    {
        const float* bg = bias_g + (size_t)blockIdx.x * (HEADS * ATOMS_PER_MOL * 8);
#pragma unroll
        for (int i = 0; i < 2; ++i) {
            const int flat = (tid * 2 + i) * 4;       // f32 index, 0..4092
            const int hh = flat >> 9;                 // head
            const int rem = flat & 511;               // atom*8 + pt
            *(float4*)((float*)bias_lds + hh * 520 + rem) = *(const float4*)(bg + flat);
        }
        if (tid < 64) bias_lds[tid >> 3][ATOMS_PER_MOL][tid & 7] = 0.0f;  // pad row
    }
    __syncthreads();

    const int m = point_batch[j0];
    const int mbase = m * ATOMS_PER_MOL;

    // ---------------- Phase 2+3: wave = 1 head ---------------------------
    const int c = lane & 15, kgrp = lane >> 4;
    const int h = wave;
    {
        // A fragment: Q rows = points (rows 8-15 duplicate 0-7, outputs unused)
        const bf16x8 aq = *(const bf16x8*)((const short*)qb +
                          (size_t)(j0 + (c & 7)) * HIDDEN + h * HEAD_DIM + kgrp * 8);

        // QK^T: one MFMA per 16-atom tile (K=32 = head_dim)
        f32x4 sacc[4];
#pragma unroll
        for (int t = 0; t < 4; ++t) {
            const bf16x8 bk_ = *(const bf16x8*)((const short*)kb +
                               (size_t)(mbase + c + 16 * t) * HIDDEN + h * HEAD_DIM + kgrp * 8);
            sacc[t] = __builtin_amdgcn_mfma_f32_16x16x32_bf16(
                aq, bk_, (f32x4){0.f, 0.f, 0.f, 0.f}, 0, 0, 0);
        }

        // scores + bias, then softmax over atoms (reduce across 16-lane c-group)
        float s[4][4];   // [tile][reg = pt row]
#pragma unroll
        for (int t = 0; t < 4; ++t) {
            const f32x4 bv = *(const f32x4*)&bias_lds[h][c + 16 * t][kgrp * 4];
#pragma unroll
            for (int r = 0; r < 4; ++r)
                s[t][r] = sacc[t][r] * scale + bv[r];
        }
#pragma unroll
        for (int r = 0; r < 4; ++r) {
            float mx = fmaxf(fmaxf(s[0][r], s[1][r]), fmaxf(s[2][r], s[3][r]));
#pragma unroll
            for (int off = 1; off <= 8; off <<= 1)
                mx = fmaxf(mx, __shfl_xor(mx, off));
            float e0 = __expf(s[0][r] - mx);
            float e1 = __expf(s[1][r] - mx);
            float e2 = __expf(s[2][r] - mx);
            float e3 = __expf(s[3][r] - mx);
            float ss = e0 + e1 + e2 + e3;
#pragma unroll
            for (int off = 1; off <= 8; off <<= 1)
                ss += __shfl_xor(ss, off);
            const float inv = 1.0f / ss;
            if (kgrp < 2) {   // rows 0-7 = valid points
                const int pt = kgrp * 4 + r;
                p_lds[h][pt][c + 16 * 0] = __float2bfloat16(e0 * inv);
                p_lds[h][pt][c + 16 * 1] = __float2bfloat16(e1 * inv);
                p_lds[h][pt][c + 16 * 2] = __float2bfloat16(e2 * inv);
                p_lds[h][pt][c + 16 * 3] = __float2bfloat16(e3 * inv);
            }
        }

        // PV: A = P (LDS, row=pt), B = V (molecule-tiled [col][atom])
        const short* vbase = (const short*)vtm + (size_t)m * (HIDDEN * ATOMS_PER_MOL);
#pragma unroll
        for (int t2 = 0; t2 < 2; ++t2) {
            f32x4 pacc = (f32x4){0.f, 0.f, 0.f, 0.f};
#pragma unroll
            for (int ks = 0; ks < 2; ++ks) {
                const bf16x8 ap = *(const bf16x8*)&p_lds[h][c & 7][ks * 32 + kgrp * 8];
                const bf16x8 bvv = *(const bf16x8*)(vbase +
                                   (size_t)(h * HEAD_DIM + t2 * 16 + c) * ATOMS_PER_MOL +
                                   ks * 32 + kgrp * 8);
                pacc = __builtin_amdgcn_mfma_f32_16x16x32_bf16(ap, bvv, pacc, 0, 0, 0);
            }
            if (kgrp < 2) {
#pragma unroll
                for (int r = 0; r < 4; ++r)
                    agg_lds[kgrp * 4 + r][h * HEAD_DIM + t2 * 16 + c] = __float2bfloat16(pacc[r]);
            }
        }
    }
    __syncthreads();

    // ---------------- Phase 4: out-projection MFMA (wave = 32 cols) ------
    const int c0 = wave * 32;
    const int lrow = lane & 15, kgrp2 = lane >> 4;
    bf16x8 af[8];
    const bf16x8 zf = {0, 0, 0, 0, 0, 0, 0, 0};
#pragma unroll
    for (int ks = 0; ks < 8; ++ks)
        af[ks] = (lrow < 8) ? *(const bf16x8*)(&agg_lds[lrow & 7][kgrp2 * 8 + ks * 32]) : zf;

    f32x4 oacc[2];
#pragma unroll
    for (int cc = 0; cc < 2; ++cc) oacc[cc] = (f32x4){0.f, 0.f, 0.f, 0.f};
#pragma unroll
    for (int cc = 0; cc < 2; ++cc) {
        const short* Wr = (const short*)WoT + (size_t)(c0 + cc * 16 + lrow) * HIDDEN + kgrp2 * 8;
#pragma unroll
        for (int ks = 0; ks < 8; ++ks)
            oacc[cc] = __builtin_amdgcn_mfma_f32_16x16x32_bf16(
                af[ks], *(const bf16x8*)(Wr + ks * 32), oacc[cc], 0, 0, 0);
    }

    const int colb = lane & 15;
    const int rowb = (lane >> 4) * 4;
#pragma unroll
    for (int cc = 0; cc < 2; ++cc) {
        const int cgl = c0 + cc * 16 + colb;
        const float bias_o = bo[cgl];
#pragma unroll
        for (int rg = 0; rg < 4; ++rg) {
            const int rl = rowb + rg;
            if (rl < 8)
                x_lds[rl][cgl] = oacc[cc][rg] + bias_o + h_point[(size_t)(j0 + rl) * HIDDEN + cgl];
        }
    }
    __syncthreads();

    // ---------------- LN: 512 threads, col = tid&255, 4 rows each --------
    const int col = tid & 255;
    const int half = tid >> 8;             // 0: rows 0-3, 1: rows 4-7
    const int ln = col & 63, wv = col >> 6;
    float xv[4];
#pragma unroll
    for (int r = 0; r < 4; ++r) {
        const int rr = half * 4 + r;
        xv[r] = x_lds[rr][col];
        float s = xv[r], qq = xv[r] * xv[r];
#pragma unroll
        for (int off = 32; off > 0; off >>= 1) {
            s += __shfl_xor(s, off);
            qq += __shfl_xor(qq, off);
        }
        if (ln == 0) { red_s[rr][wv] = s; red_q[rr][wv] = qq; }
    }
    __syncthreads();

    const float gc = gamma[col], bc = beta[col];
#pragma unroll
    for (int r = 0; r < 4; ++r) {
        const int rr = half * 4 + r;
        const float mean = (red_s[rr][0] + red_s[rr][1] + red_s[rr][2] + red_s[rr][3]) * (1.0f / HIDDEN);
        const float ex2  = (red_q[rr][0] + red_q[rr][1] + red_q[rr][2] + red_q[rr][3]) * (1.0f / HIDDEN);
        const float var = ex2 - mean * mean;
        out[(size_t)(j0 + rr) * HIDDEN + col] = (xv[r] - mean) * rsqrtf(var + 1e-5f) * gc + bc;
    }
}

// -------------------------------------------------------------------------
extern "C" void kernel_launch(void* const* d_in, const int* in_sizes, int n_in,
                              void* d_out, int out_size, void* d_ws, size_t ws_size,
                              hipStream_t stream) {
    const float* h_point   = (const float*)d_in[0];
    const float* h_atom    = (const float*)d_in[1];
    const float* pos_point = (const float*)d_in[2];
    const float* pos_atom  = (const float*)d_in[3];
    const float* Wq        = (const float*)d_in[4];
    const float* bq        = (const float*)d_in[5];
    const float* Wk        = (const float*)d_in[6];
    const float* bk        = (const float*)d_in[7];
    const float* Wv        = (const float*)d_in[8];
    const float* bv        = (const float*)d_in[9];
    const float* Wo        = (const float*)d_in[10];
    const float* bo        = (const float*)d_in[11];
    const float* W_rbf     = (const float*)d_in[12];
    const float* b_rbf     = (const float*)d_in[13];
    const float* centers   = (const float*)d_in[14];
    const float* gamma     = (const float*)d_in[15];
    const float* beta      = (const float*)d_in[16];
    const int*   point_batch = (const int*)d_in[17];
    const int*   atom_batch  = (const int*)d_in[18];
    float* out = (float*)d_out;

    __hip_bfloat16* qb = (__hip_bfloat16*)d_ws;                 // 4096*256 bf16
    __hip_bfloat16* kb = qb + (size_t)K_PTS * HIDDEN;           // 2048*256 bf16
    __hip_bfloat16* vtm = kb + (size_t)N_ATOMS * HIDDEN;        // 32 x 256 x 64 bf16
    __hip_bfloat16* WqT = vtm + (size_t)HIDDEN * N_ATOMS;
    __hip_bfloat16* WkT = WqT + HIDDEN * HIDDEN;
    __hip_bfloat16* WvT = WkT + HIDDEN * HIDDEN;
    __hip_bfloat16* WoT = WvT + HIDDEN * HIDDEN;
    float* bias_g = (float*)(WoT + HIDDEN * HIDDEN);            // 512*8*64*8 f32 = 8MB

    prepW_kernel<<<256, 256, 0, stream>>>(Wq, Wk, Wv, Wo, WqT, WkT, WvT, WoT);

    qkv_bias_kernel<<<896, 256, 0, stream>>>(h_point, h_atom,
                                             WqT, bq, qb,
                                             WkT, bk, kb,
                                             WvT, bv, vtm,
                                             pos_point, pos_atom,
                                             W_rbf, b_rbf, centers,
                                             point_batch, atom_batch, bias_g);

    attn_mfma8_kernel<<<K_PTS / 8, 512, 0, stream>>>(qb, kb, vtm,
                                                     bias_g, point_batch,
                                                     WoT, bo, h_point, gamma, beta,
                                                     out);
}

// Round 14
// 129.493 us; speedup vs baseline: 1.0902x; 1.0661x over previous
//
#include <hip/hip_runtime.h>
#include <hip/hip_bf16.h>

#define HIDDEN 256
#define HEADS 8
#define HEAD_DIM 32
#define NUM_RBF 32
#define K_PTS 4096
#define N_ATOMS 2048
#define B_MOL 32
#define ATOMS_PER_MOL (N_ATOMS / B_MOL)   // 64

typedef __attribute__((ext_vector_type(8))) short bf16x8;
typedef __attribute__((ext_vector_type(4))) float f32x4;

// -------------------------------------------------------------------------
// K0: prepW — weight transposes (4 mats x 64 tiles of 32x32). WT[c][d]=bf16(W[d][c])
// -------------------------------------------------------------------------
__global__ __launch_bounds__(256) void prepW_kernel(
    const float* __restrict__ Wq, const float* __restrict__ Wk,
    const float* __restrict__ Wv, const float* __restrict__ Wo,
    __hip_bfloat16* __restrict__ WqT, __hip_bfloat16* __restrict__ WkT,
    __hip_bfloat16* __restrict__ WvT, __hip_bfloat16* __restrict__ WoT) {
    __shared__ float tile[32][33];
    const int t = blockIdx.x, tid = threadIdx.x;
    const int matId = t >> 6, tileId = t & 63;
    const int tr = (tileId >> 3) * 32, tc = (tileId & 7) * 32;
    const float* __restrict__ Ws = (matId == 0) ? Wq : (matId == 1) ? Wk : (matId == 2) ? Wv : Wo;
    __hip_bfloat16* __restrict__ Wd = (matId == 0) ? WqT : (matId == 1) ? WkT : (matId == 2) ? WvT : WoT;

    const int r = tid >> 3, cq = (tid & 7) * 4;
    const float4 in = *(const float4*)&Ws[(size_t)(tr + r) * HIDDEN + tc + cq];
    tile[r][cq + 0] = in.x; tile[r][cq + 1] = in.y;
    tile[r][cq + 2] = in.z; tile[r][cq + 3] = in.w;
    __syncthreads();
    __hip_bfloat16 o[4];
    o[0] = __float2bfloat16(tile[cq + 0][r]);
    o[1] = __float2bfloat16(tile[cq + 1][r]);
    o[2] = __float2bfloat16(tile[cq + 2][r]);
    o[3] = __float2bfloat16(tile[cq + 3][r]);
    *(uint2*)(Wd + (size_t)(tc + r) * HIDDEN + tr + cq) = *(const uint2*)o;
}

// -------------------------------------------------------------------------
// K1: fused QKV MFMA GEMM, col-split: each block = 16 rows x 128 cols.
// blocks [0,512): Q (256 row-blocks x 2 col-halves);
// blocks [512,768): K+V (128 row-blocks x 2 col-halves).
// Q -> bf16 row-major; K -> bf16 row-major; V -> mol-tiled vtm[mol][col][atom].
// -------------------------------------------------------------------------
__device__ __forceinline__ bf16x8 cvt8(const float* p) {
    const float4 lo = *(const float4*)p;
    const float4 hi = *(const float4*)(p + 4);
    __hip_bfloat16 t[8];
    t[0] = __float2bfloat16(lo.x); t[1] = __float2bfloat16(lo.y);
    t[2] = __float2bfloat16(lo.z); t[3] = __float2bfloat16(lo.w);
    t[4] = __float2bfloat16(hi.x); t[5] = __float2bfloat16(hi.y);
    t[6] = __float2bfloat16(hi.z); t[7] = __float2bfloat16(hi.w);
    return *(const bf16x8*)t;
}

__global__ __launch_bounds__(256) void qkv4_kernel(
    const float* __restrict__ hp, const float* __restrict__ ha,
    const __hip_bfloat16* __restrict__ WqT, const float* __restrict__ bq, __hip_bfloat16* __restrict__ qb,
    const __hip_bfloat16* __restrict__ WkT, const float* __restrict__ bk, __hip_bfloat16* __restrict__ kb,
    const __hip_bfloat16* __restrict__ WvT, const float* __restrict__ bv, __hip_bfloat16* __restrict__ vtm) {
    const int b = blockIdx.x;
    const bool isQ = (b < 512);
    const int rb = isQ ? (b >> 1) : ((b - 512) >> 1);
    const int ch = isQ ? (b & 1) : ((b - 512) & 1);
    const float* __restrict__ A = isQ ? hp : ha;
    const __hip_bfloat16* __restrict__ W0T = isQ ? WqT : WkT;
    const float* __restrict__ b0 = isQ ? bq : bk;
    const int r0 = rb * 16;

    const int wave = threadIdx.x >> 6, lane = threadIdx.x & 63;
    const int c0 = ch * 128 + wave * 32;          // this wave's 32-col slice
    const int lrow = lane & 15, kgrp = lane >> 4;

    bf16x8 af[8];
    const float* Arow = A + (size_t)(r0 + lrow) * HIDDEN + kgrp * 8;
#pragma unroll
    for (int ks = 0; ks < 8; ++ks)
        af[ks] = cvt8(Arow + ks * 32);

    f32x4 acc0[2], acc1[2];
#pragma unroll
    for (int cc = 0; cc < 2; ++cc) {
        acc0[cc] = (f32x4){0.f, 0.f, 0.f, 0.f};
        acc1[cc] = (f32x4){0.f, 0.f, 0.f, 0.f};
    }

#pragma unroll
    for (int cc = 0; cc < 2; ++cc) {
        const short* W0r = (const short*)W0T + (size_t)(c0 + cc * 16 + lrow) * HIDDEN + kgrp * 8;
#pragma unroll
        for (int ks = 0; ks < 8; ++ks)
            acc0[cc] = __builtin_amdgcn_mfma_f32_16x16x32_bf16(
                af[ks], *(const bf16x8*)(W0r + ks * 32), acc0[cc], 0, 0, 0);
        if (!isQ) {
            const short* W1r = (const short*)WvT + (size_t)(c0 + cc * 16 + lrow) * HIDDEN + kgrp * 8;
#pragma unroll
            for (int ks = 0; ks < 8; ++ks)
                acc1[cc] = __builtin_amdgcn_mfma_f32_16x16x32_bf16(
                    af[ks], *(const bf16x8*)(W1r + ks * 32), acc1[cc], 0, 0, 0);
        }
    }

    const int colb = lane & 15;
    const int rowb = (lane >> 4) * 4;
#pragma unroll
    for (int cc = 0; cc < 2; ++cc) {
        const int cgl = c0 + cc * 16 + colb;
        const float bias0 = b0[cgl];
        if (isQ) {
#pragma unroll
            for (int rg = 0; rg < 4; ++rg)
                qb[(size_t)(r0 + rowb + rg) * HIDDEN + cgl] = __float2bfloat16(acc0[cc][rg] + bias0);
        } else {
            const float bias1 = bv[cgl];
            const int mol = r0 >> 6;
            const int abase = (r0 & 63) + rowb;
            __hip_bfloat16 vo[4];
#pragma unroll
            for (int rg = 0; rg < 4; ++rg) {
                kb[(size_t)(r0 + rowb + rg) * HIDDEN + cgl] = __float2bfloat16(acc0[cc][rg] + bias0);
                vo[rg] = __float2bfloat16(acc1[cc][rg] + bias1);
            }
            *(uint2*)(vtm + (size_t)mol * (HIDDEN * ATOMS_PER_MOL) +
                      (size_t)cgl * ATOMS_PER_MOL + abase) = *(const uint2*)vo;
        }
    }
}

// -------------------------------------------------------------------------
// K2: attn_mfma8 — block = 8 points, 8 WAVES (512 threads), cap 64 VGPR.
// Phase 1 (wave = 1 point, lane = atom): RBF bias -> bias_lds[h][atom][pt]
// Phase 2+3 (wave = 1 head): QK^T MFMA + softmax + PV MFMA
// Phase 4: out-proj MFMA (wave = 32 cols) + residual + LN (thread = 4 rows)
// -------------------------------------------------------------------------
#define AGG_PAD (HIDDEN + 16)

__global__ __launch_bounds__(512, 8) void attn_mfma8_kernel(
    const __hip_bfloat16* __restrict__ qb, const __hip_bfloat16* __restrict__ kb,
    const __hip_bfloat16* __restrict__ vtm,
    const float* __restrict__ pos_point, const float* __restrict__ pos_atom,
    const float* __restrict__ W_rbf, const float* __restrict__ b_rbf,
    const float* __restrict__ centers,
    const int* __restrict__ point_batch, const int* __restrict__ atom_batch,
    const __hip_bfloat16* __restrict__ WoT, const float* __restrict__ bo,
    const float* __restrict__ h_point,
    const float* __restrict__ gamma, const float* __restrict__ beta,
    float* __restrict__ out) {
    __shared__ float wrbf_lds[NUM_RBF][HEADS];      // 1 KB
    __shared__ float cent_lds[NUM_RBF];
    __shared__ float brbf_lds[HEADS];
    __shared__ float bias_lds[HEADS][ATOMS_PER_MOL + 1][8];  // 16.6 KB (+1 row pad)
    __shared__ __hip_bfloat16 p_lds[HEADS][8][72];  // 9 KB [h][pt][atom]
    __shared__ __hip_bfloat16 agg_lds[8][AGG_PAD];  // 4.3 KB
    __shared__ float x_lds[8][260];                 // 8.3 KB
    __shared__ float red_s[8][4];
    __shared__ float red_q[8][4];

    const int tid = threadIdx.x, wave = tid >> 6, lane = tid & 63;
    const int j0 = blockIdx.x * 8;
    const float scale = 0.17677669529663687f;  // 32^-0.5

    if (tid < NUM_RBF * HEADS) ((float*)wrbf_lds)[tid] = W_rbf[tid];
    if (tid < NUM_RBF) cent_lds[tid] = centers[tid];
    if (tid < HEADS) brbf_lds[tid] = b_rbf[tid];
    if (tid < 64) bias_lds[tid >> 3][ATOMS_PER_MOL][tid & 7] = 0.0f;  // pad row
    __syncthreads();

    const int m = point_batch[j0];
    const int mbase = m * ATOMS_PER_MOL;

    // ---------------- Phase 1: RBF bias (wave = 1 point, lane = atom) ----
    {
        const int n = mbase + lane;
        const bool valid = (atom_batch[n] == m);
        const int j = j0 + wave;

        const float dx = pos_point[j * 3 + 0] - pos_atom[n * 3 + 0];
        const float dy = pos_point[j * 3 + 1] - pos_atom[n * 3 + 1];
        const float dz = pos_point[j * 3 + 2] - pos_atom[n * 3 + 2];
        const float dist = sqrtf(fmaxf(dx * dx + dy * dy + dz * dz, 0.0f));

        float bias[HEADS];
#pragma unroll
        for (int h = 0; h < HEADS; ++h) bias[h] = brbf_lds[h];
#pragma unroll
        for (int r = 0; r < NUM_RBF; ++r) {
            const float dd = dist - cent_lds[r];
            const float e = __expf(-16.0f * dd * dd);   // width = (8/32)^2 -> -1/w = -16
#pragma unroll
            for (int h = 0; h < HEADS; ++h)
                bias[h] += e * wrbf_lds[r][h];
        }
#pragma unroll
        for (int h = 0; h < HEADS; ++h)
            bias_lds[h][lane][wave] = valid ? bias[h] : -1e30f;
    }
    __syncthreads();

    // ---------------- Phase 2+3: wave = 1 head ---------------------------
    const int c = lane & 15, kgrp = lane >> 4;
    const int h = wave;
    {
        // A fragment: Q rows = points (rows 8-15 duplicate 0-7, outputs unused)
        const bf16x8 aq = *(const bf16x8*)((const short*)qb +
                          (size_t)(j0 + (c & 7)) * HIDDEN + h * HEAD_DIM + kgrp * 8);

        // QK^T: one MFMA per 16-atom tile (K=32 = head_dim)
        f32x4 sacc[4];
#pragma unroll
        for (int t = 0; t < 4; ++t) {
            const bf16x8 bk_ = *(const bf16x8*)((const short*)kb +
                               (size_t)(mbase + c + 16 * t) * HIDDEN + h * HEAD_DIM + kgrp * 8);
            sacc[t] = __builtin_amdgcn_mfma_f32_16x16x32_bf16(
                aq, bk_, (f32x4){0.f, 0.f, 0.f, 0.f}, 0, 0, 0);
        }

        // scores + bias, then softmax over atoms (reduce across 16-lane c-group)
        float s[4][4];   // [tile][reg = pt row]
#pragma unroll
        for (int t = 0; t < 4; ++t) {
            const f32x4 bv = *(const f32x4*)&bias_lds[h][c + 16 * t][kgrp * 4];
#pragma unroll
            for (int r = 0; r < 4; ++r)
                s[t][r] = sacc[t][r] * scale + bv[r];
        }
#pragma unroll
        for (int r = 0; r < 4; ++r) {
            float mx = fmaxf(fmaxf(s[0][r], s[1][r]), fmaxf(s[2][r], s[3][r]));
#pragma unroll
            for (int off = 1; off <= 8; off <<= 1)
                mx = fmaxf(mx, __shfl_xor(mx, off));
            float e0 = __expf(s[0][r] - mx);
            float e1 = __expf(s[1][r] - mx);
            float e2 = __expf(s[2][r] - mx);
            float e3 = __expf(s[3][r] - mx);
            float ss = e0 + e1 + e2 + e3;
#pragma unroll
            for (int off = 1; off <= 8; off <<= 1)
                ss += __shfl_xor(ss, off);
            const float inv = 1.0f / ss;
            if (kgrp < 2) {   // rows 0-7 = valid points
                const int pt = kgrp * 4 + r;
                p_lds[h][pt][c + 16 * 0] = __float2bfloat16(e0 * inv);
                p_lds[h][pt][c + 16 * 1] = __float2bfloat16(e1 * inv);
                p_lds[h][pt][c + 16 * 2] = __float2bfloat16(e2 * inv);
                p_lds[h][pt][c + 16 * 3] = __float2bfloat16(e3 * inv);
            }
        }

        // PV: A = P (LDS, row=pt), B = V (molecule-tiled [col][atom]),
        // 2 n-tiles x 2 k-steps; B fragment = 16B contiguous per lane.
        const short* vbase = (const short*)vtm + (size_t)m * (HIDDEN * ATOMS_PER_MOL);
#pragma unroll
        for (int t2 = 0; t2 < 2; ++t2) {
            f32x4 pacc = (f32x4){0.f, 0.f, 0.f, 0.f};
#pragma unroll
            for (int ks = 0; ks < 2; ++ks) {
                const bf16x8 ap = *(const bf16x8*)&p_lds[h][c & 7][ks * 32 + kgrp * 8];
                const bf16x8 bvv = *(const bf16x8*)(vbase +
                                   (size_t)(h * HEAD_DIM + t2 * 16 + c) * ATOMS_PER_MOL +
                                   ks * 32 + kgrp * 8);
                pacc = __builtin_amdgcn_mfma_f32_16x16x32_bf16(ap, bvv, pacc, 0, 0, 0);
            }
            if (kgrp < 2) {
#pragma unroll
                for (int r = 0; r < 4; ++r)
                    agg_lds[kgrp * 4 + r][h * HEAD_DIM + t2 * 16 + c] = __float2bfloat16(pacc[r]);
            }
        }
    }
    __syncthreads();

    // ---------------- Phase 4: out-projection MFMA (wave = 32 cols) ------
    const int c0 = wave * 32;
    const int lrow = lane & 15, kgrp2 = lane >> 4;
    bf16x8 af[8];
    const bf16x8 zf = {0, 0, 0, 0, 0, 0, 0, 0};
#pragma unroll
    for (int ks = 0; ks < 8; ++ks)
        af[ks] = (lrow < 8) ? *(const bf16x8*)(&agg_lds[lrow & 7][kgrp2 * 8 + ks * 32]) : zf;

    f32x4 oacc[2];
#pragma unroll
    for (int cc = 0; cc < 2; ++cc) oacc[cc] = (f32x4){0.f, 0.f, 0.f, 0.f};
#pragma unroll
    for (int cc = 0; cc < 2; ++cc) {
        const short* Wr = (const short*)WoT + (size_t)(c0 + cc * 16 + lrow) * HIDDEN + kgrp2 * 8;
#pragma unroll
        for (int ks = 0; ks < 8; ++ks)
            oacc[cc] = __builtin_amdgcn_mfma_f32_16x16x32_bf16(
                af[ks], *(const bf16x8*)(Wr + ks * 32), oacc[cc], 0, 0, 0);
    }

    const int colb = lane & 15;
    const int rowb = (lane >> 4) * 4;
#pragma unroll
    for (int cc = 0; cc < 2; ++cc) {
        const int cgl = c0 + cc * 16 + colb;
        const float bias_o = bo[cgl];
#pragma unroll
        for (int rg = 0; rg < 4; ++rg) {
            const int rl = rowb + rg;
            if (rl < 8)
                x_lds[rl][cgl] = oacc[cc][rg] + bias_o + h_point[(size_t)(j0 + rl) * HIDDEN + cgl];
        }
    }
    __syncthreads();

    // ---------------- LN: 512 threads, col = tid&255, 4 rows each --------
    const int col = tid & 255;
    const int half = tid >> 8;             // 0: rows 0-3, 1: rows 4-7
    const int ln = col & 63, wv = col >> 6;
    float xv[4];
#pragma unroll
    for (int r = 0; r < 4; ++r) {
        const int rr = half * 4 + r;
        xv[r] = x_lds[rr][col];
        float s = xv[r], qq = xv[r] * xv[r];
#pragma unroll
        for (int off = 32; off > 0; off >>= 1) {
            s += __shfl_xor(s, off);
            qq += __shfl_xor(qq, off);
        }
        if (ln == 0) { red_s[rr][wv] = s; red_q[rr][wv] = qq; }
    }
    __syncthreads();

    const float gc = gamma[col], bc = beta[col];
#pragma unroll
    for (int r = 0; r < 4; ++r) {
        const int rr = half * 4 + r;
        const float mean = (red_s[rr][0] + red_s[rr][1] + red_s[rr][2] + red_s[rr][3]) * (1.0f / HIDDEN);
        const float ex2  = (red_q[rr][0] + red_q[rr][1] + red_q[rr][2] + red_q[rr][3]) * (1.0f / HIDDEN);
        const float var = ex2 - mean * mean;
        out[(size_t)(j0 + rr) * HIDDEN + col] = (xv[r] - mean) * rsqrtf(var + 1e-5f) * gc + bc;
    }
}

// -------------------------------------------------------------------------
extern "C" void kernel_launch(void* const* d_in, const int* in_sizes, int n_in,
                              void* d_out, int out_size, void* d_ws, size_t ws_size,
                              hipStream_t stream) {
    const float* h_point   = (const float*)d_in[0];
    const float* h_atom    = (const float*)d_in[1];
    const float* pos_point = (const float*)d_in[2];
    const float* pos_atom  = (const float*)d_in[3];
    const float* Wq        = (const float*)d_in[4];
    const float* bq        = (const float*)d_in[5];
    const float* Wk        = (const float*)d_in[6];
    const float* bk        = (const float*)d_in[7];
    const float* Wv        = (const float*)d_in[8];
    const float* bv        = (const float*)d_in[9];
    const float* Wo        = (const float*)d_in[10];
    const float* bo        = (const float*)d_in[11];
    const float* W_rbf     = (const float*)d_in[12];
    const float* b_rbf     = (const float*)d_in[13];
    const float* centers   = (const float*)d_in[14];
    const float* gamma     = (const float*)d_in[15];
    const float* beta      = (const float*)d_in[16];
    const int*   point_batch = (const int*)d_in[17];
    const int*   atom_batch  = (const int*)d_in[18];
    float* out = (float*)d_out;

    __hip_bfloat16* qb = (__hip_bfloat16*)d_ws;                 // 4096*256 bf16
    __hip_bfloat16* kb = qb + (size_t)K_PTS * HIDDEN;           // 2048*256 bf16
    __hip_bfloat16* vtm = kb + (size_t)N_ATOMS * HIDDEN;        // 32 x 256 x 64 bf16 (mol-tiled V^T)
    __hip_bfloat16* WqT = vtm + (size_t)HIDDEN * N_ATOMS;
    __hip_bfloat16* WkT = WqT + HIDDEN * HIDDEN;
    __hip_bfloat16* WvT = WkT + HIDDEN * HIDDEN;
    __hip_bfloat16* WoT = WvT + HIDDEN * HIDDEN;

    prepW_kernel<<<256, 256, 0, stream>>>(Wq, Wk, Wv, Wo, WqT, WkT, WvT, WoT);

    qkv4_kernel<<<768, 256, 0, stream>>>(h_point, h_atom,
                                         WqT, bq, qb,
                                         WkT, bk, kb,
                                         WvT, bv, vtm);

    attn_mfma8_kernel<<<K_PTS / 8, 512, 0, stream>>>(qb, kb, vtm,
                                                     pos_point, pos_atom,
                                                     W_rbf, b_rbf, centers,
                                                     point_batch, atom_batch,
                                                     WoT, bo, h_point, gamma, beta,
                                                     out);
}